// Round 7
// baseline (619.644 us; speedup 1.0000x reference)
//
#include <hip/hip_runtime.h>
#include <hip/hip_cooperative_groups.h>

namespace cg = cooperative_groups;

// GCN layer: out = relu(segment_sum(edge_val * (x@W + b)[edge_col] -> edge_row))
// N=100000 nodes, E=1600000 edges, 256 -> 128 features, fp32 in/out.
//
// Round 13: fuse the whole CSR build (bhist+bscan+bin+place, 4 kernels +
// memset + 3 dependency gaps) into ONE cooperative kernel. r12 analysis:
// aggregate (65us) is fabric-byte-bound (r12's 8-deep MLP changed nothing),
// while the CSR block's kernels all sit just under the 62us profile cutoff
// -> likely ~130us combined, the real top cost. Fusion also removes the
// erow re-read and runs place at 768 blocks (5/CU LDS) vs 256 (1/CU).
//   A: per-block LDS hist over 768 buckets (131 rows each) + RELATIVE
//      cursor reservation (atomicAdd(cursor_rel) -> post-sync cursor_rel
//      IS the totals array; no separate bucket_tot pass). bk/rl stashed
//      in registers -> erow read once.
//   B: every block redundantly scans the 768 totals in LDS -> abs bases.
//   C: scatter into per-(block,bucket) runs (write-combined).
//   D: per-bucket place: LDS stage + row-hist + scan + row_start +
//      LDS-cursor scatter. threadfence + grid.sync for cross-XCD visibility.
// gemm (r9) and aggregate (r12) unchanged.

constexpr int kNodes = 100000;
constexpr int kEdges = 1600000;
constexpr int kInF   = 256;
constexpr int kOutF  = 128;
constexpr int kTiles = kNodes / 16;                 // 6250
constexpr int kGemmBlocks = 1250;                   // 5 tiles per block

constexpr int kNB  = 768;                           // buckets (= csr grid)
constexpr int kRB  = 131;                           // rows/bucket (768*131 >= N)
constexpr int kCap = 2432;                          // LDS-staged edges/bucket (mean 2083, max~2300)
constexpr int kCsrBlocks = kNB;
constexpr int kEPB = (kEdges + kCsrBlocks - 1) / kCsrBlocks;  // 2084 edges/block

constexpr int kTileCap = 1024;                      // staged edges per 16-node agg tile (8KB)

typedef __attribute__((ext_vector_type(8))) short short8;
typedef __attribute__((ext_vector_type(8))) unsigned short ush8;
typedef __attribute__((ext_vector_type(4))) float floatx4;

__device__ inline unsigned short f2bf_rne(float f) {
    unsigned int u = __float_as_uint(f);
    unsigned int r = u + 0x7FFFu + ((u >> 16) & 1u);
    return (unsigned short)(r >> 16);
}
__device__ inline float bf2f(unsigned short h) {
    return __uint_as_float(((unsigned int)h) << 16);
}

// 8 fp32 -> 8 bf16 (RNE) via 4x v_cvt_pk_bf16_f32.
__device__ inline short8 cvt8_bf16(const float4 a, const float4 b) {
    union { short8 s; unsigned int u[4]; } r;
    asm("v_cvt_pk_bf16_f32 %0, %1, %2" : "=v"(r.u[0]) : "v"(a.x), "v"(a.y));
    asm("v_cvt_pk_bf16_f32 %0, %1, %2" : "=v"(r.u[1]) : "v"(a.z), "v"(a.w));
    asm("v_cvt_pk_bf16_f32 %0, %1, %2" : "=v"(r.u[2]) : "v"(b.x), "v"(b.y));
    asm("v_cvt_pk_bf16_f32 %0, %1, %2" : "=v"(r.u[3]) : "v"(b.z), "v"(b.w));
    return r.s;
}

// async 16B global->LDS (dest = wave-uniform base + lane*16)
__device__ inline void gload_lds16(const void* g, void* l) {
    __builtin_amdgcn_global_load_lds(
        (const __attribute__((address_space(1))) unsigned int*)g,
        (__attribute__((address_space(3))) unsigned int*)l,
        16, 0, 0);
}

// ---------------------------------------------------------------------------
// GEMM: support_bf[N][128] = bf16(x[N][256] @ W[256][128] + b)  (r9, kept)
// ---------------------------------------------------------------------------
__global__ __launch_bounds__(256) void gcn_gemm(const float* __restrict__ x,
                                                const float* __restrict__ W,
                                                const float* __restrict__ b,
                                                unsigned short* __restrict__ support) {
    __shared__ __align__(16) float lbuf[2][4096];   // 2 x 16KB

    const int lane = threadIdx.x & 63;
    const int wv   = threadIdx.x >> 6;
    const int rowl = lane & 15;
    const int quad = lane >> 4;
    const int colbase = wv * 32;

    short8 bfrag[2][8];
#pragma unroll
    for (int ct = 0; ct < 2; ++ct) {
        const int col = colbase + ct * 16 + rowl;
#pragma unroll
        for (int kc = 0; kc < 8; ++kc) {
            const int kb = kc * 32 + quad * 8;
            short8 f;
#pragma unroll
            for (int j = 0; j < 8; ++j)
                f[j] = (short)f2bf_rne(W[(size_t)(kb + j) * kOutF + col]);
            bfrag[ct][kc] = f;
        }
    }
    const float bias0 = b[colbase + rowl];
    const float bias1 = b[colbase + 16 + rowl];

    const int G = gridDim.x;
    int t = blockIdx.x;

#define GEMM_STAGE(buf_, tile_)                                                   \
    do {                                                                          \
        const float* tb_ = x + (size_t)(tile_) * 16 * kInF;                       \
        _Pragma("unroll")                                                         \
        for (int i_ = 0; i_ < 4; ++i_) {                                          \
            const int row_ = i_ * 4 + wv;                                         \
            gload_lds16(tb_ + (size_t)row_ * kInF + ((lane ^ (row_ & 7)) << 2),   \
                        &lbuf[buf_][row_ << 8]);                                  \
        }                                                                         \
    } while (0)

    if (t < kTiles) GEMM_STAGE(0, t);
    int cur = 0;

    for (; t < kTiles; t += G) {
        const int tn = t + G;
        asm volatile("s_waitcnt vmcnt(0)" ::: "memory");
        __syncthreads();
        if (tn < kTiles) GEMM_STAGE(cur ^ 1, tn);

        const int r0 = t * 16;
        const float* base = &lbuf[cur][rowl << 8];
        const int rsw = rowl & 7;
        floatx4 acc0 = {0.f, 0.f, 0.f, 0.f};
        floatx4 acc1 = {0.f, 0.f, 0.f, 0.f};
#pragma unroll
        for (int kc = 0; kc < 8; ++kc) {
            const int g0 = (kc << 3) + (quad << 1);
            const float4 v0 = *reinterpret_cast<const float4*>(base + ((g0 ^ rsw) << 2));
            const float4 v1 = *reinterpret_cast<const float4*>(base + (((g0 + 1) ^ rsw) << 2));
            const short8 a = cvt8_bf16(v0, v1);
            acc0 = __builtin_amdgcn_mfma_f32_16x16x32_bf16(a, bfrag[0][kc], acc0, 0, 0, 0);
            acc1 = __builtin_amdgcn_mfma_f32_16x16x32_bf16(a, bfrag[1][kc], acc1, 0, 0, 0);
        }
#pragma unroll
        for (int reg = 0; reg < 4; ++reg) {
            const size_t rbase = (size_t)(r0 + quad * 4 + reg) * kOutF + colbase;
            support[rbase + rowl]      = f2bf_rne(acc0[reg] + bias0);
            support[rbase + 16 + rowl] = f2bf_rne(acc1[reg] + bias1);
        }
        cur ^= 1;
    }
#undef GEMM_STAGE
}

// ---------------------------------------------------------------------------
// Fused CSR build (cooperative, grid = 768 blocks = 768 buckets).
// packed.x = (row_local<<17)|col between C and D; D strips to col only.
// ---------------------------------------------------------------------------
__global__ __launch_bounds__(256, 3) void gcn_csr(const int* __restrict__ erow,
                                                  const int* __restrict__ ecol,
                                                  const float* __restrict__ eval,
                                                  int* __restrict__ cursor_rel,   // [kNB], zeroed
                                                  int2* __restrict__ packed,
                                                  int* __restrict__ row_start) {
    __shared__ int2 st[kCap];    // 19456 B (D stage)
    __shared__ int  cnt[kNB];    //  3072 B (A counts -> abs block base)
    __shared__ int  rk[kNB];     //  3072 B (C rank / D row cursors)
    __shared__ int  s2[kNB];     //  3072 B (B scan / D row counts+scan)
    const int tid = threadIdx.x;
    const int blk = blockIdx.x;
    cg::grid_group grid = cg::this_grid();

    const int eb0 = blk * kEPB;
    const int eb1 = min(eb0 + kEPB, kEdges);

    // ---- A: count per bucket (LDS), then reserve RELATIVE run offsets ----
    for (int i = tid; i < kNB; i += 256) { cnt[i] = 0; rk[i] = 0; }
    __syncthreads();
    unsigned int bkrl[9];        // (bk<<8)|rl stash; erow read exactly once
#pragma unroll
    for (int i = 0; i < 9; ++i) {
        const int e = eb0 + i * 256 + tid;
        bkrl[i] = 0xFFFFFFFFu;
        if (e < eb1) {
            const int r = erow[e];
            const unsigned int bk = (unsigned int)r / (unsigned int)kRB;
            bkrl[i] = (bk << 8) | (unsigned int)(r - (int)bk * kRB);
            atomicAdd(&cnt[bk], 1);
        }
    }
    __syncthreads();
    for (int i = tid; i < kNB; i += 256) {
        const int c = cnt[i];
        cnt[i] = c ? atomicAdd(&cursor_rel[i], c) : 0;   // relative base in bucket i
    }
    __threadfence();
    grid.sync();                 // cursor_rel now = per-bucket totals

    // ---- B: redundant per-block scan of totals -> absolute bases ----
    {
        for (int j = 0; j < 3; ++j) s2[tid + j * 256] = cursor_rel[tid + j * 256];
        __syncthreads();
        for (int off = 1; off < kNB; off <<= 1) {
            int v0 = 0, v1 = 0, v2 = 0;
            if (tid        >= off) v0 = s2[tid        - off];
            if (tid + 256  >= off) v1 = s2[tid + 256  - off];
            if (tid + 512  >= off) v2 = s2[tid + 512  - off];
            __syncthreads();
            s2[tid]       += v0;
            s2[tid + 256] += v1;
            s2[tid + 512] += v2;
            __syncthreads();
        }
    }
    // this block's bucket extent (registers, before s2 is reused in D)
    const int inclb = s2[blk];
    const int sbase = blk ? s2[blk - 1] : 0;
    const int ssize = inclb - sbase;
    // cnt: relative -> absolute block base per bucket
    for (int i = tid; i < kNB; i += 256)
        cnt[i] += (i ? s2[i - 1] : 0);
    __syncthreads();

    // ---- C: scatter edges into bucket runs (write-combined) ----
#pragma unroll
    for (int i = 0; i < 9; ++i) {
        const int e = eb0 + i * 256 + tid;
        if (e < eb1) {
            const unsigned int br = bkrl[i];
            const int bk = (int)(br >> 8);
            const int rl = (int)(br & 0xFFu);
            const int c  = ecol[e];
            const float v = eval[e];
            const int pos = cnt[bk] + atomicAdd(&rk[bk], 1);
            packed[pos] = make_int2((rl << 17) | c, __float_as_int(v));
        }
    }
    __threadfence();
    grid.sync();                 // all packed writes visible

    // ---- D: per-bucket place (this block's bucket = blk) ----
    const int r0 = blk * kRB;
    if (r0 >= kNodes) return;
    const int r1 = min(r0 + kRB, kNodes);
    const int NR = r1 - r0;
    const int staged = min(ssize, kCap);

    s2[tid] = 0;                 // row counters (NR <= 131 <= 256)
    __syncthreads();
    for (int i = tid; i < staged; i += 256) {
        const int2 p = packed[sbase + i];
        st[i] = p;
        atomicAdd(&s2[p.x >> 17], 1);
    }
    int2 tail[8];
    int  nt = 0;
    for (int i = kCap + tid; i < ssize; i += 256) {
        if (nt < 8) {
            tail[nt] = packed[sbase + i];
            atomicAdd(&s2[tail[nt].x >> 17], 1);
            ++nt;
        }
    }
    __syncthreads();             // all reads + counts done (in-place safe)

    // inclusive scan of s2[0..255]
    for (int off = 1; off < 256; off <<= 1) {
        const int v = (tid >= off) ? s2[tid - off] : 0;
        __syncthreads();
        s2[tid] += v;
        __syncthreads();
    }
    if (tid < NR) {
        const int excl = tid ? s2[tid - 1] : 0;
        row_start[r0 + tid] = sbase + excl;
        rk[tid] = excl;
    }
    if (blk == 0 && tid == 0) row_start[kNodes] = kEdges;
    __syncthreads();

    for (int i = tid; i < staged; i += 256) {
        const int2 p  = st[i];
        const int pos = sbase + atomicAdd(&rk[p.x >> 17], 1);
        packed[pos] = make_int2(p.x & 0x1FFFF, p.y);
    }
#pragma unroll
    for (int t = 0; t < 8; ++t) {
        if (t < nt) {
            const int2 p  = tail[t];
            const int pos = sbase + atomicAdd(&rk[p.x >> 17], 1);
            packed[pos] = make_int2(p.x & 0x1FFFF, p.y);
        }
    }
}

// ---------------------------------------------------------------------------
// Aggregate + ReLU (r12, unchanged): 16 nodes x 16 lanes/block; tile's edge
// records bulk-staged in LDS; 8 independent 16B gathers in flight per lane.
// ---------------------------------------------------------------------------
__global__ __launch_bounds__(256) void gcn_aggregate(const int* __restrict__ row_start,
                                                     const int2* __restrict__ packed,
                                                     const unsigned short* __restrict__ support,
                                                     float* __restrict__ out) {
    __shared__ int2 ep[kTileCap];
    const int n0 = blockIdx.x * 16;
    const int e0 = row_start[n0];
    const int eN = row_start[n0 + 16] - e0;
    const int nStage = min(eN, kTileCap);
    for (int i = threadIdx.x; i < nStage; i += 256)
        ep[i] = packed[e0 + i];
    __syncthreads();

    const int n  = n0 + (threadIdx.x >> 4);
    const int f8 = (threadIdx.x & 15) * 8;
    const unsigned short* sb = support + f8;
    const int s0 = row_start[n]     - e0;
    const int s1 = row_start[n + 1] - e0;

    float acc[8];
#pragma unroll
    for (int j = 0; j < 8; ++j) acc[j] = 0.f;

    if (eN <= kTileCap) {
        int i = s0;
        for (; i + 7 < s1; i += 8) {
            int2 p[8];
#pragma unroll
            for (int k = 0; k < 8; ++k) p[k] = ep[i + k];
            ush8 g[8];
#pragma unroll
            for (int k = 0; k < 8; ++k)
                g[k] = *reinterpret_cast<const ush8*>(sb + (size_t)p[k].x * kOutF);
#pragma unroll
            for (int k = 0; k < 8; ++k) {
                const float v = __int_as_float(p[k].y);
#pragma unroll
                for (int j = 0; j < 8; ++j) acc[j] += v * bf2f(g[k][j]);
            }
        }
        for (; i < s1; ++i) {
            const int2 p = ep[i];
            const float v = __int_as_float(p.y);
            const ush8 g = *reinterpret_cast<const ush8*>(sb + (size_t)p.x * kOutF);
#pragma unroll
            for (int j = 0; j < 8; ++j) acc[j] += v * bf2f(g[j]);
        }
    } else {
        int i = s0;
        for (; i + 3 < s1; i += 4) {
            const int2 p0 = packed[e0 + i];
            const int2 p1 = packed[e0 + i + 1];
            const int2 p2 = packed[e0 + i + 2];
            const int2 p3 = packed[e0 + i + 3];
            const ush8 a0 = *reinterpret_cast<const ush8*>(sb + (size_t)p0.x * kOutF);
            const ush8 a1 = *reinterpret_cast<const ush8*>(sb + (size_t)p1.x * kOutF);
            const ush8 a2 = *reinterpret_cast<const ush8*>(sb + (size_t)p2.x * kOutF);
            const ush8 a3 = *reinterpret_cast<const ush8*>(sb + (size_t)p3.x * kOutF);
            const float v0 = __int_as_float(p0.y), v1 = __int_as_float(p1.y);
            const float v2 = __int_as_float(p2.y), v3 = __int_as_float(p3.y);
#pragma unroll
            for (int j = 0; j < 8; ++j) {
                acc[j] += v0 * bf2f(a0[j]);
                acc[j] += v1 * bf2f(a1[j]);
                acc[j] += v2 * bf2f(a2[j]);
                acc[j] += v3 * bf2f(a3[j]);
            }
        }
        for (; i < s1; ++i) {
            const int2 p = packed[e0 + i];
            const float v = __int_as_float(p.y);
            const ush8 a = *reinterpret_cast<const ush8*>(sb + (size_t)p.x * kOutF);
#pragma unroll
            for (int j = 0; j < 8; ++j) acc[j] += v * bf2f(a[j]);
        }
    }

    float4 o0 = make_float4(fmaxf(acc[0], 0.f), fmaxf(acc[1], 0.f),
                            fmaxf(acc[2], 0.f), fmaxf(acc[3], 0.f));
    float4 o1 = make_float4(fmaxf(acc[4], 0.f), fmaxf(acc[5], 0.f),
                            fmaxf(acc[6], 0.f), fmaxf(acc[7], 0.f));
    *reinterpret_cast<float4*>(out + (size_t)n * kOutF + f8)     = o0;
    *reinterpret_cast<float4*>(out + (size_t)n * kOutF + f8 + 4) = o1;
}

extern "C" void kernel_launch(void* const* d_in, const int* in_sizes, int n_in,
                              void* d_out, int out_size, void* d_ws, size_t ws_size,
                              hipStream_t stream) {
    const float* x    = (const float*)d_in[0];
    const int*   erow = (const int*)  d_in[1];
    const int*   ecol = (const int*)  d_in[2];
    const float* eval = (const float*)d_in[3];
    const float* W    = (const float*)d_in[4];
    const float* b    = (const float*)d_in[5];
    float* out = (float*)d_out;

    char* ws = (char*)d_ws;
    unsigned short* support = (unsigned short*)(ws);       // 25,600,000 B (row-major [N][128])
    int2* packed     = (int2*)(ws + 25600000);             // 12,800,000 B
    int*  row_start  = (int*) (ws + 38400000);             //    400,004 B
    int*  cursor_rel = (int*) (ws + 38800008);             //      3,072 B

    // 1) support = bf16(x@W + b)
    gcn_gemm<<<kGemmBlocks, 256, 0, stream>>>(x, W, b, support);

    // 2) fused CSR build (cooperative: hist -> scan -> bin -> place)
    hipMemsetAsync(cursor_rel, 0, kNB * sizeof(int), stream);
    void* cargs[] = {(void*)&erow, (void*)&ecol, (void*)&eval,
                     (void*)&cursor_rel, (void*)&packed, (void*)&row_start};
    hipLaunchCooperativeKernel((const void*)gcn_csr, dim3(kCsrBlocks), dim3(256),
                               cargs, 0, stream);

    // 3) aggregate + relu
    gcn_aggregate<<<kTiles, 256, 0, stream>>>(row_start, packed, support, out);
}

// Round 8
// 331.481 us; speedup vs baseline: 1.8693x; 1.8693x over previous
//
#include <hip/hip_runtime.h>

// GCN layer: out = relu(segment_sum(edge_val * (x@W + b)[edge_col] -> edge_row))
// N=100000 nodes, E=1600000 edges, 256 -> 128 features, fp32 in/out.
//
// Round 14: REVERT r13's cooperative fusion (gcn_csr=354us: grid.sync +
// device fences serialized the machine; 2.7-edge runs killed combining).
// Back to r12's 4-kernel CSR build, re-parameterized for occupancy:
//   kNB 256 -> 1024 buckets (kRB=98, kCap=1792 -> 15.3KB LDS): place goes
//   from 256 blocks @ 1 block/CU (63KB LDS, 12.5% occ) to 1024 blocks @
//   4 blocks/CU -- 16x resident waves for identical traffic.
//   bin/bhist: 256 blocks x 6250 edges keeps (block,bucket) runs at ~6
//   edges (write-combined); flush atomics unchanged at 262K. bin re-reads
//   erow in the scatter pass instead of register-stashing (24/thread).
//   bscan: 1024-wide single-block scan (4 elems/thread).
// gemm (r9: global_load_lds + dbuf + XOR swizzle) and aggregate (r12:
// LDS-staged edge records, 8-deep gather) byte-identical to r12.

constexpr int kNodes = 100000;
constexpr int kEdges = 1600000;
constexpr int kInF   = 256;
constexpr int kOutF  = 128;
constexpr int kTiles = kNodes / 16;                 // 6250
constexpr int kGemmBlocks = 1250;                   // 5 tiles per block

constexpr int kNB  = 1024;                          // buckets
constexpr int kRB  = 98;                            // rows/bucket (1024*98 >= N)
constexpr int kCap = 1792;                          // LDS-staged edges/bucket (mean 1562)
constexpr int kBinBlocks = 256;
constexpr int kEPB = kEdges / kBinBlocks;           // 6250 edges/block

constexpr int kTileCap = 1024;                      // staged edges per 16-node agg tile

typedef __attribute__((ext_vector_type(8))) short short8;
typedef __attribute__((ext_vector_type(8))) unsigned short ush8;
typedef __attribute__((ext_vector_type(4))) float floatx4;

__device__ inline unsigned short f2bf_rne(float f) {
    unsigned int u = __float_as_uint(f);
    unsigned int r = u + 0x7FFFu + ((u >> 16) & 1u);
    return (unsigned short)(r >> 16);
}
__device__ inline float bf2f(unsigned short h) {
    return __uint_as_float(((unsigned int)h) << 16);
}

// 8 fp32 -> 8 bf16 (RNE) via 4x v_cvt_pk_bf16_f32.
__device__ inline short8 cvt8_bf16(const float4 a, const float4 b) {
    union { short8 s; unsigned int u[4]; } r;
    asm("v_cvt_pk_bf16_f32 %0, %1, %2" : "=v"(r.u[0]) : "v"(a.x), "v"(a.y));
    asm("v_cvt_pk_bf16_f32 %0, %1, %2" : "=v"(r.u[1]) : "v"(a.z), "v"(a.w));
    asm("v_cvt_pk_bf16_f32 %0, %1, %2" : "=v"(r.u[2]) : "v"(b.x), "v"(b.y));
    asm("v_cvt_pk_bf16_f32 %0, %1, %2" : "=v"(r.u[3]) : "v"(b.z), "v"(b.w));
    return r.s;
}

// async 16B global->LDS (dest = wave-uniform base + lane*16)
__device__ inline void gload_lds16(const void* g, void* l) {
    __builtin_amdgcn_global_load_lds(
        (const __attribute__((address_space(1))) unsigned int*)g,
        (__attribute__((address_space(3))) unsigned int*)l,
        16, 0, 0);
}

// ---------------------------------------------------------------------------
// GEMM: support_bf[N][128] = bf16(x[N][256] @ W[256][128] + b)  (r9, kept)
// ---------------------------------------------------------------------------
__global__ __launch_bounds__(256) void gcn_gemm(const float* __restrict__ x,
                                                const float* __restrict__ W,
                                                const float* __restrict__ b,
                                                unsigned short* __restrict__ support) {
    __shared__ __align__(16) float lbuf[2][4096];   // 2 x 16KB

    const int lane = threadIdx.x & 63;
    const int wv   = threadIdx.x >> 6;
    const int rowl = lane & 15;
    const int quad = lane >> 4;
    const int colbase = wv * 32;

    short8 bfrag[2][8];
#pragma unroll
    for (int ct = 0; ct < 2; ++ct) {
        const int col = colbase + ct * 16 + rowl;
#pragma unroll
        for (int kc = 0; kc < 8; ++kc) {
            const int kb = kc * 32 + quad * 8;
            short8 f;
#pragma unroll
            for (int j = 0; j < 8; ++j)
                f[j] = (short)f2bf_rne(W[(size_t)(kb + j) * kOutF + col]);
            bfrag[ct][kc] = f;
        }
    }
    const float bias0 = b[colbase + rowl];
    const float bias1 = b[colbase + 16 + rowl];

    const int G = gridDim.x;
    int t = blockIdx.x;

#define GEMM_STAGE(buf_, tile_)                                                   \
    do {                                                                          \
        const float* tb_ = x + (size_t)(tile_) * 16 * kInF;                       \
        _Pragma("unroll")                                                         \
        for (int i_ = 0; i_ < 4; ++i_) {                                          \
            const int row_ = i_ * 4 + wv;                                         \
            gload_lds16(tb_ + (size_t)row_ * kInF + ((lane ^ (row_ & 7)) << 2),   \
                        &lbuf[buf_][row_ << 8]);                                  \
        }                                                                         \
    } while (0)

    if (t < kTiles) GEMM_STAGE(0, t);
    int cur = 0;

    for (; t < kTiles; t += G) {
        const int tn = t + G;
        asm volatile("s_waitcnt vmcnt(0)" ::: "memory");
        __syncthreads();
        if (tn < kTiles) GEMM_STAGE(cur ^ 1, tn);

        const int r0 = t * 16;
        const float* base = &lbuf[cur][rowl << 8];
        const int rsw = rowl & 7;
        floatx4 acc0 = {0.f, 0.f, 0.f, 0.f};
        floatx4 acc1 = {0.f, 0.f, 0.f, 0.f};
#pragma unroll
        for (int kc = 0; kc < 8; ++kc) {
            const int g0 = (kc << 3) + (quad << 1);
            const float4 v0 = *reinterpret_cast<const float4*>(base + ((g0 ^ rsw) << 2));
            const float4 v1 = *reinterpret_cast<const float4*>(base + (((g0 + 1) ^ rsw) << 2));
            const short8 a = cvt8_bf16(v0, v1);
            acc0 = __builtin_amdgcn_mfma_f32_16x16x32_bf16(a, bfrag[0][kc], acc0, 0, 0, 0);
            acc1 = __builtin_amdgcn_mfma_f32_16x16x32_bf16(a, bfrag[1][kc], acc1, 0, 0, 0);
        }
#pragma unroll
        for (int reg = 0; reg < 4; ++reg) {
            const size_t rbase = (size_t)(r0 + quad * 4 + reg) * kOutF + colbase;
            support[rbase + rowl]      = f2bf_rne(acc0[reg] + bias0);
            support[rbase + 16 + rowl] = f2bf_rne(acc1[reg] + bias1);
        }
        cur ^= 1;
    }
#undef GEMM_STAGE
}

// ---------------------------------------------------------------------------
// Bucket histogram: 256 blocks x 6250 edges, LDS hist over 1024 buckets,
// one global atomic per (block,bucket) with nonzero count (<=262K total).
// ---------------------------------------------------------------------------
__global__ __launch_bounds__(256) void gcn_bhist(const int* __restrict__ erow,
                                                 int* __restrict__ bucket_tot) {
    __shared__ int cnt[kNB];
    const int tid = threadIdx.x;
    for (int i = tid; i < kNB; i += 256) cnt[i] = 0;
    __syncthreads();
    const int eb0 = blockIdx.x * kEPB;
    const int eb1 = min(eb0 + kEPB, kEdges);
    for (int e = eb0 + tid; e < eb1; e += 256)
        atomicAdd(&cnt[(unsigned int)erow[e] / (unsigned int)kRB], 1);
    __syncthreads();
    for (int i = tid; i < kNB; i += 256) {
        const int c = cnt[i];
        if (c) atomicAdd(&bucket_tot[i], c);
    }
}

// ---------------------------------------------------------------------------
// Bucket scan: one block, 1024-wide exclusive scan (4 elems/thread).
// ---------------------------------------------------------------------------
__global__ __launch_bounds__(256) void gcn_bscan(const int* __restrict__ bucket_tot,
                                                 int* __restrict__ bucket_base,
                                                 int* __restrict__ cursor,
                                                 int* __restrict__ row_start) {
    __shared__ int s[kNB];
    const int tid = threadIdx.x;
    int t[4];
#pragma unroll
    for (int j = 0; j < 4; ++j) {
        const int idx = tid + j * 256;
        t[j] = bucket_tot[idx];
        s[idx] = t[j];
    }
    __syncthreads();
    for (int off = 1; off < kNB; off <<= 1) {
        int v[4];
#pragma unroll
        for (int j = 0; j < 4; ++j) {
            const int idx = tid + j * 256;
            v[j] = (idx >= off) ? s[idx - off] : 0;
        }
        __syncthreads();
#pragma unroll
        for (int j = 0; j < 4; ++j) s[tid + j * 256] += v[j];
        __syncthreads();
    }
#pragma unroll
    for (int j = 0; j < 4; ++j) {
        const int idx = tid + j * 256;
        const int excl = s[idx] - t[j];
        bucket_base[idx] = excl;
        cursor[idx]      = excl;
    }
    if (tid == 255) {
        bucket_base[kNB]  = kEdges;
        row_start[kNodes] = kEdges;
    }
}

// ---------------------------------------------------------------------------
// Bin: scatter edges into bucket runs (write-combined, ~6-edge runs).
// Pass 1 counts (erow only), flush reserves absolute run bases, pass 2
// re-reads erow/ecol/eval and scatters. packed.x = (row_local<<17)|col.
// ---------------------------------------------------------------------------
__global__ __launch_bounds__(256) void gcn_bin(const int* __restrict__ erow,
                                               const int* __restrict__ ecol,
                                               const float* __restrict__ eval,
                                               int* __restrict__ cursor,
                                               int2* __restrict__ packed) {
    __shared__ int cnt[kNB];   // counts -> absolute run base after flush
    __shared__ int rk[kNB];    // run rank
    const int tid = threadIdx.x;
    const int eb0 = blockIdx.x * kEPB;
    const int eb1 = min(eb0 + kEPB, kEdges);
    for (int i = tid; i < kNB; i += 256) { cnt[i] = 0; rk[i] = 0; }
    __syncthreads();
#pragma unroll 4
    for (int e = eb0 + tid; e < eb1; e += 256)
        atomicAdd(&cnt[(unsigned int)erow[e] / (unsigned int)kRB], 1);
    __syncthreads();
    for (int i = tid; i < kNB; i += 256) {
        const int c = cnt[i];
        cnt[i] = c ? atomicAdd(&cursor[i], c) : 0;
    }
    __syncthreads();
#pragma unroll 4
    for (int e = eb0 + tid; e < eb1; e += 256) {
        const int r = erow[e];
        const unsigned int bk = (unsigned int)r / (unsigned int)kRB;
        const int rl = r - (int)bk * kRB;
        const int pos = cnt[bk] + atomicAdd(&rk[bk], 1);
        packed[pos] = make_int2((rl << 17) | ecol[e], __float_as_int(eval[e]));
    }
}

// ---------------------------------------------------------------------------
// Place: 1024 blocks (one per bucket), 15.3KB LDS -> 4 blocks/CU resident.
// Stage bucket in LDS (+reg tail), LDS row hist (<=98), 128-wide scan,
// write row_start, scatter via LDS cursors. In-place safe (reads precede
// writes across the barrier).
// ---------------------------------------------------------------------------
__global__ __launch_bounds__(256) void gcn_place(const int* __restrict__ bucket_base,
                                                 int* __restrict__ row_start,
                                                 int2* __restrict__ packed) {
    __shared__ int2 st[kCap];    // 14,336 B
    __shared__ int  s[128];      //     512 B (row counts -> inclusive scan)
    __shared__ int  rcur[kRB];   //     392 B (row cursors)
    const int bk = blockIdx.x;
    const int r0 = bk * kRB;
    if (r0 >= kNodes) return;
    const int r1 = min(r0 + kRB, kNodes);
    const int NR = r1 - r0;
    const int bb = bucket_base[bk];
    const int s1 = bucket_base[bk + 1];
    const int size   = s1 - bb;
    const int staged = min(size, kCap);
    const int tid = threadIdx.x;

    if (tid < 128) s[tid] = 0;
    __syncthreads();

    for (int i = tid; i < staged; i += 256) {
        const int2 p = packed[bb + i];
        st[i] = p;
        atomicAdd(&s[p.x >> 17], 1);
    }
    int2 tail[8];
    int  nt = 0;
    for (int i = kCap + tid; i < size; i += 256) {
        if (nt < 8) {
            tail[nt] = packed[bb + i];
            atomicAdd(&s[tail[nt].x >> 17], 1);
            ++nt;
        }
    }
    __syncthreads();   // all reads + counts done (in-place safe)

    for (int off = 1; off < 128; off <<= 1) {
        int v = 0;
        if (tid < 128 && tid >= off) v = s[tid - off];
        __syncthreads();
        if (tid < 128) s[tid] += v;
        __syncthreads();
    }
    if (tid < NR) {
        const int excl = tid ? s[tid - 1] : 0;
        row_start[r0 + tid] = bb + excl;
        rcur[tid] = excl;
    }
    __syncthreads();

    for (int i = tid; i < staged; i += 256) {
        const int2 p  = st[i];
        const int pos = bb + atomicAdd(&rcur[p.x >> 17], 1);
        packed[pos] = make_int2(p.x & 0x1FFFF, p.y);
    }
#pragma unroll
    for (int t = 0; t < 8; ++t) {
        if (t < nt) {
            const int2 p  = tail[t];
            const int pos = bb + atomicAdd(&rcur[p.x >> 17], 1);
            packed[pos] = make_int2(p.x & 0x1FFFF, p.y);
        }
    }
}

// ---------------------------------------------------------------------------
// Aggregate + ReLU (r12, unchanged): 16 nodes x 16 lanes/block; tile's edge
// records bulk-staged in LDS; 8 independent 16B gathers in flight per lane.
// ---------------------------------------------------------------------------
__global__ __launch_bounds__(256) void gcn_aggregate(const int* __restrict__ row_start,
                                                     const int2* __restrict__ packed,
                                                     const unsigned short* __restrict__ support,
                                                     float* __restrict__ out) {
    __shared__ int2 ep[kTileCap];
    const int n0 = blockIdx.x * 16;
    const int e0 = row_start[n0];
    const int eN = row_start[n0 + 16] - e0;
    const int nStage = min(eN, kTileCap);
    for (int i = threadIdx.x; i < nStage; i += 256)
        ep[i] = packed[e0 + i];
    __syncthreads();

    const int n  = n0 + (threadIdx.x >> 4);
    const int f8 = (threadIdx.x & 15) * 8;
    const unsigned short* sb = support + f8;
    const int s0 = row_start[n]     - e0;
    const int s1 = row_start[n + 1] - e0;

    float acc[8];
#pragma unroll
    for (int j = 0; j < 8; ++j) acc[j] = 0.f;

    if (eN <= kTileCap) {
        int i = s0;
        for (; i + 7 < s1; i += 8) {
            int2 p[8];
#pragma unroll
            for (int k = 0; k < 8; ++k) p[k] = ep[i + k];
            ush8 g[8];
#pragma unroll
            for (int k = 0; k < 8; ++k)
                g[k] = *reinterpret_cast<const ush8*>(sb + (size_t)p[k].x * kOutF);
#pragma unroll
            for (int k = 0; k < 8; ++k) {
                const float v = __int_as_float(p[k].y);
#pragma unroll
                for (int j = 0; j < 8; ++j) acc[j] += v * bf2f(g[k][j]);
            }
        }
        for (; i < s1; ++i) {
            const int2 p = ep[i];
            const float v = __int_as_float(p.y);
            const ush8 g = *reinterpret_cast<const ush8*>(sb + (size_t)p.x * kOutF);
#pragma unroll
            for (int j = 0; j < 8; ++j) acc[j] += v * bf2f(g[j]);
        }
    } else {
        int i = s0;
        for (; i + 3 < s1; i += 4) {
            const int2 p0 = packed[e0 + i];
            const int2 p1 = packed[e0 + i + 1];
            const int2 p2 = packed[e0 + i + 2];
            const int2 p3 = packed[e0 + i + 3];
            const ush8 a0 = *reinterpret_cast<const ush8*>(sb + (size_t)p0.x * kOutF);
            const ush8 a1 = *reinterpret_cast<const ush8*>(sb + (size_t)p1.x * kOutF);
            const ush8 a2 = *reinterpret_cast<const ush8*>(sb + (size_t)p2.x * kOutF);
            const ush8 a3 = *reinterpret_cast<const ush8*>(sb + (size_t)p3.x * kOutF);
            const float v0 = __int_as_float(p0.y), v1 = __int_as_float(p1.y);
            const float v2 = __int_as_float(p2.y), v3 = __int_as_float(p3.y);
#pragma unroll
            for (int j = 0; j < 8; ++j) {
                acc[j] += v0 * bf2f(a0[j]);
                acc[j] += v1 * bf2f(a1[j]);
                acc[j] += v2 * bf2f(a2[j]);
                acc[j] += v3 * bf2f(a3[j]);
            }
        }
        for (; i < s1; ++i) {
            const int2 p = packed[e0 + i];
            const float v = __int_as_float(p.y);
            const ush8 a = *reinterpret_cast<const ush8*>(sb + (size_t)p.x * kOutF);
#pragma unroll
            for (int j = 0; j < 8; ++j) acc[j] += v * bf2f(a[j]);
        }
    }

    float4 o0 = make_float4(fmaxf(acc[0], 0.f), fmaxf(acc[1], 0.f),
                            fmaxf(acc[2], 0.f), fmaxf(acc[3], 0.f));
    float4 o1 = make_float4(fmaxf(acc[4], 0.f), fmaxf(acc[5], 0.f),
                            fmaxf(acc[6], 0.f), fmaxf(acc[7], 0.f));
    *reinterpret_cast<float4*>(out + (size_t)n * kOutF + f8)     = o0;
    *reinterpret_cast<float4*>(out + (size_t)n * kOutF + f8 + 4) = o1;
}

extern "C" void kernel_launch(void* const* d_in, const int* in_sizes, int n_in,
                              void* d_out, int out_size, void* d_ws, size_t ws_size,
                              hipStream_t stream) {
    const float* x    = (const float*)d_in[0];
    const int*   erow = (const int*)  d_in[1];
    const int*   ecol = (const int*)  d_in[2];
    const float* eval = (const float*)d_in[3];
    const float* W    = (const float*)d_in[4];
    const float* b    = (const float*)d_in[5];
    float* out = (float*)d_out;

    char* ws = (char*)d_ws;
    unsigned short* support = (unsigned short*)(ws);       // 25,600,000 B (row-major [N][128])
    int2* packed      = (int2*)(ws + 25600000);            // 12,800,000 B
    int*  row_start   = (int*) (ws + 38400000);            //    400,004 B
    int*  bucket_tot  = (int*) (ws + 38800008);            //      4,096 B
    int*  bucket_base = (int*) (ws + 38804104);            //      4,100 B
    int*  cursor      = (int*) (ws + 38808204);            //      4,096 B

    // 1) support = bf16(x@W + b)
    gcn_gemm<<<kGemmBlocks, 256, 0, stream>>>(x, W, b, support);

    // 2) CSR build: hist -> scan -> bin -> place
    hipMemsetAsync(bucket_tot, 0, kNB * sizeof(int), stream);
    gcn_bhist<<<kBinBlocks, 256, 0, stream>>>(erow, bucket_tot);
    gcn_bscan<<<1, 256, 0, stream>>>(bucket_tot, bucket_base, cursor, row_start);
    gcn_bin  <<<kBinBlocks, 256, 0, stream>>>(erow, ecol, eval, cursor, packed);
    gcn_place<<<kNB, 256, 0, stream>>>(bucket_base, row_start, packed);

    // 3) aggregate + relu
    gcn_aggregate<<<kTiles, 256, 0, stream>>>(row_start, packed, support, out);
}